// Round 9
// baseline (256.031 us; speedup 1.0000x reference)
//
#include <hip/hip_runtime.h>
#include <stdint.h>

#define BB 64
#define SS 512
#define DPP 12   // padded head dim (48B rows -> float4 aligned)
#define EPSF 1e-5f

typedef float v2f __attribute__((ext_vector_type(2)));

// ---------------- K1: LN1 + QKV projection ----------------
// grid 512 x 256. Block = 64 rows; wave = j-part (32 cols), lane = row.
__global__ __launch_bounds__(256) void k_ln_qkv(
    const float* __restrict__ x, const float* __restrict__ g, const float* __restrict__ be,
    const float* __restrict__ Wq, const float* __restrict__ bq,
    const float* __restrict__ Wk, const float* __restrict__ bk,
    const float* __restrict__ Wv, const float* __restrict__ bv,
    float* __restrict__ qo, float* __restrict__ ko, float* __restrict__ vo)
{
    __shared__ float sWT[40][128];   // [i][j], j=0..119 valid (q|k|v), 120..127 zero
    __shared__ float sBias[128];
    __shared__ float sG[40], sBt[40];
    __shared__ float sX[64][41];
    __shared__ float sOut[64][129];

    const int tid = threadIdx.x;
    for (int idx = tid; idx < 5120; idx += 256) {
        int i = idx >> 7, j = idx & 127;
        float val = 0.f;
        if (j < 40)       val = Wq[i * 40 + j];
        else if (j < 80)  val = Wk[i * 40 + (j - 40)];
        else if (j < 120) val = Wv[i * 40 + (j - 80)];
        sWT[i][j] = val;
    }
    if (tid < 128) {
        int j = tid;
        float val = 0.f;
        if (j < 40)       val = bq[j];
        else if (j < 80)  val = bk[j - 40];
        else if (j < 120) val = bv[j - 80];
        sBias[j] = val;
    }
    if (tid < 40) { sG[tid] = g[tid]; sBt[tid] = be[tid]; }

    const float4* xblk = (const float4*)(x + (size_t)blockIdx.x * 64 * 40);
    for (int idx = tid; idx < 640; idx += 256) {
        float4 u = xblk[idx];
        int fl = idx * 4;
        int r = fl / 40, c = fl - r * 40;
        sX[r][c] = u.x; sX[r][c + 1] = u.y; sX[r][c + 2] = u.z; sX[r][c + 3] = u.w;
    }
    __syncthreads();

    const int lane = tid & 63;
    const int part = tid >> 6;
    const int j0 = part * 32;

    // fused LN stats: one LDS pass
    float s1 = 0.f, s2 = 0.f;
#pragma unroll 8
    for (int i = 0; i < 40; i++) { float v = sX[lane][i]; s1 += v; s2 += v * v; }
    const float mu = s1 * 0.025f;
    const float rs = rsqrtf(s2 * 0.025f - mu * mu + EPSF);

    float acc[32];
#pragma unroll
    for (int jj = 0; jj < 32; jj++) acc[jj] = sBias[j0 + jj];
#pragma unroll 4
    for (int i = 0; i < 40; i++) {
        const float hi = (sX[lane][i] - mu) * rs * sG[i] + sBt[i];
        const float4* wrow = (const float4*)&sWT[i][j0];
#pragma unroll
        for (int c = 0; c < 8; c++) {
            float4 wv = wrow[c];
            acc[c * 4 + 0] += hi * wv.x;
            acc[c * 4 + 1] += hi * wv.y;
            acc[c * 4 + 2] += hi * wv.z;
            acc[c * 4 + 3] += hi * wv.w;
        }
    }
#pragma unroll
    for (int jj = 0; jj < 32; jj++) sOut[lane][j0 + jj] = acc[jj];
    __syncthreads();

    const int row0 = blockIdx.x * 64;
    const int b4 = (row0 >> 9) * 4, s0 = row0 & 511;
    for (int fi = tid; fi < 2304; fi += 256) {
        int region = fi / 192;
        int kk = fi - region * 192;
        int w = region >> 2, hh = region & 3;
        int r = kk / 3, gg = kk - r * 3;
        int bj = w * 40 + hh * 10 + gg * 4;
        float4 val;
        val.x = sOut[r][bj];
        val.y = sOut[r][bj + 1];
        val.z = (gg == 2) ? 0.f : sOut[r][bj + 2];
        val.w = (gg == 2) ? 0.f : sOut[r][bj + 3];
        float* op = (w == 0) ? qo : (w == 1) ? ko : vo;
        *(float4*)(op + ((size_t)((b4 + hh) * 512 + s0 + r)) * DPP + gg * 4) = val;
    }
}

// ---------------- K2: attention v9 ----------------
// grid 512 = bh x q-half (256 q). block 512 = 8 waves = k-eighths (64 keys).
// QPT=4, LDS-staged K/V (48KB), packed-fp32 math. Merge via column-major
// LDS atomics aliased onto the dead staging buffer. 2 blk/CU x 8 waves.
__global__ __launch_bounds__(512, 4) void k_attn(
    const float* __restrict__ qg, const float* __restrict__ kg,
    const float* __restrict__ vg, float* __restrict__ ctx)
{
    __shared__ float smem[12288];        // 48KB: sK+sV, then aliased as sAcc[11][256]
    float4* sK = (float4*)smem;          // [1536]
    float4* sV = sK + 1536;              // [1536]

    const int tid = threadIdx.x;
    const int bh = blockIdx.x >> 1;
    const int qh = blockIdx.x & 1;

    const float4* kp = (const float4*)(kg + (size_t)bh * 512 * DPP);
    const float4* vp = (const float4*)(vg + (size_t)bh * 512 * DPP);
    for (int idx = tid; idx < 1536; idx += 512) { sK[idx] = kp[idx]; sV[idx] = vp[idx]; }

    const int lane = tid & 63;
    const int wave = tid >> 6;           // k-eighth
    const int kbase = wave * 64;

    const float cscale = 1.4426950408889634f / 3.1622776601683795f;  // log2e/sqrt(10)
    v2f q[4][5];
#pragma unroll
    for (int jj = 0; jj < 4; jj++) {
        const float2* qp = (const float2*)(qg + ((size_t)bh * 512 + qh * 256 + jj * 64 + lane) * DPP);
#pragma unroll
        for (int c = 0; c < 5; c++) {
            float2 u = qp[c];
            v2f t; t.x = u.x * cscale; t.y = u.y * cscale;
            q[jj][c] = t;
        }
    }

    float l[4] = {0.f, 0.f, 0.f, 0.f};
    v2f a[4][5];
#pragma unroll
    for (int jj = 0; jj < 4; jj++)
#pragma unroll
        for (int d = 0; d < 5; d++) a[jj][d] = (v2f)(0.f);

    __syncthreads();

#pragma unroll 2
    for (int kt = 0; kt < 64; kt += 2) {
        const int ki = kbase + kt;
        const float4 ka0 = sK[ki * 3 + 0], ka1 = sK[ki * 3 + 1], ka2 = sK[ki * 3 + 2];
        const float4 kb0 = sK[ki * 3 + 3], kb1 = sK[ki * 3 + 4], kb2 = sK[ki * 3 + 5];
        const float4 va0 = sV[ki * 3 + 0], va1 = sV[ki * 3 + 1], va2 = sV[ki * 3 + 2];
        const float4 vb0 = sV[ki * 3 + 3], vb1 = sV[ki * 3 + 4], vb2 = sV[ki * 3 + 5];
        v2f ka[5], kb[5], va[5], vb[5];
        ka[0] = v2f{ka0.x, ka0.y}; ka[1] = v2f{ka0.z, ka0.w};
        ka[2] = v2f{ka1.x, ka1.y}; ka[3] = v2f{ka1.z, ka1.w};
        ka[4] = v2f{ka2.x, ka2.y};
        kb[0] = v2f{kb0.x, kb0.y}; kb[1] = v2f{kb0.z, kb0.w};
        kb[2] = v2f{kb1.x, kb1.y}; kb[3] = v2f{kb1.z, kb1.w};
        kb[4] = v2f{kb2.x, kb2.y};
        va[0] = v2f{va0.x, va0.y}; va[1] = v2f{va0.z, va0.w};
        va[2] = v2f{va1.x, va1.y}; va[3] = v2f{va1.z, va1.w};
        va[4] = v2f{va2.x, va2.y};
        vb[0] = v2f{vb0.x, vb0.y}; vb[1] = v2f{vb0.z, vb0.w};
        vb[2] = v2f{vb1.x, vb1.y}; vb[3] = v2f{vb1.z, vb1.w};
        vb[4] = v2f{vb2.x, vb2.y};
#pragma unroll
        for (int jj = 0; jj < 4; jj++) {
            v2f da = q[jj][0] * ka[0];
            v2f db = q[jj][0] * kb[0];
#pragma unroll
            for (int c = 1; c < 5; c++) {
                da += q[jj][c] * ka[c];
                db += q[jj][c] * kb[c];
            }
            const float pa = __builtin_amdgcn_exp2f(da.x + da.y);
            const float pb = __builtin_amdgcn_exp2f(db.x + db.y);
            l[jj] += pa + pb;
            const v2f pa2 = {pa, pa};
            const v2f pb2 = {pb, pb};
#pragma unroll
            for (int d = 0; d < 5; d++)
                a[jj][d] += pa2 * va[d] + pb2 * vb[d];
        }
    }
    __syncthreads();   // all sK/sV reads done -> safe to alias

    // zero merge buffer sAcc[11][256] = smem[0..2815]
    for (int idx = tid; idx < 2816; idx += 512) smem[idx] = 0.f;
    __syncthreads();

    // column-major atomic merge: lanes hit consecutive addresses (no conflicts)
#pragma unroll
    for (int jj = 0; jj < 4; jj++) {
        const int qq = jj * 64 + lane;
        atomicAdd(&smem[0 * 256 + qq], a[jj][0].x);
        atomicAdd(&smem[1 * 256 + qq], a[jj][0].y);
        atomicAdd(&smem[2 * 256 + qq], a[jj][1].x);
        atomicAdd(&smem[3 * 256 + qq], a[jj][1].y);
        atomicAdd(&smem[4 * 256 + qq], a[jj][2].x);
        atomicAdd(&smem[5 * 256 + qq], a[jj][2].y);
        atomicAdd(&smem[6 * 256 + qq], a[jj][3].x);
        atomicAdd(&smem[7 * 256 + qq], a[jj][3].y);
        atomicAdd(&smem[8 * 256 + qq], a[jj][4].x);
        atomicAdd(&smem[9 * 256 + qq], a[jj][4].y);
        atomicAdd(&smem[10 * 256 + qq], l[jj]);
    }
    __syncthreads();

    // normalize + write: threads 0..255, one query each
    if (tid < 256) {
        const float inv = 1.f / smem[10 * 256 + tid];
        float* op = ctx + ((size_t)bh * 512 + qh * 256 + tid) * 10;
#pragma unroll
        for (int d = 0; d < 5; d++) {
            float2 w;
            w.x = smem[(d * 2 + 0) * 256 + tid] * inv;
            w.y = smem[(d * 2 + 1) * 256 + tid] * inv;
            *(float2*)(op + d * 2) = w;
        }
    }
}

// ---------------- K3: Wo + residual + LN2 + FFN + residual ----------------
// grid 512 x 256. Block = 64 rows; wave = col-slice, lane = row.
__global__ __launch_bounds__(256) void k_out_ffn(
    const float* __restrict__ ctx, const float* __restrict__ x,
    const float* __restrict__ Wo, const float* __restrict__ bo,
    const float* __restrict__ g2, const float* __restrict__ bt2,
    const float* __restrict__ W1, const float* __restrict__ b1,
    const float* __restrict__ W2, const float* __restrict__ b2,
    float* __restrict__ out)
{
    __shared__ float sWo[40][48];
    __shared__ float sW1[40][32];
    __shared__ float sW2[20][48];
    __shared__ float sBo[40], sG2[40], sBt2[40], sB1[20], sB2[40];
    __shared__ float sCtx[64][41];
    __shared__ float sH[64][41];
    __shared__ float sIt[64][21];
    __shared__ float sSum[64][4], sSum2[64][4];

    const int tid = threadIdx.x;
    for (int idx = tid; idx < 1600; idx += 256) {
        int i = idx / 40, j = idx % 40;
        sWo[i][(j / 10) * 12 + (j % 10)] = Wo[idx];
    }
    for (int idx = tid; idx < 800; idx += 256) {
        {
            int i = idx / 20, j = idx % 20;
            sW1[i][(j / 5) * 8 + (j % 5)] = W1[idx];
        }
        {
            int i = idx / 40, j = idx % 40;
            sW2[i][(j / 10) * 12 + (j % 10)] = W2[idx];
        }
    }
    if (tid < 40) { sBo[tid] = bo[tid]; sG2[tid] = g2[tid]; sBt2[tid] = bt2[tid]; sB2[tid] = b2[tid]; }
    if (tid < 20) sB1[tid] = b1[tid];

    const int row0 = blockIdx.x * 64;
    const int b = row0 >> 9, s0 = row0 & 511;

    for (int idx = tid; idx < 640; idx += 256) {
        const int hh = idx / 160, f = idx - hh * 160;
        float4 u = *(const float4*)(ctx + ((size_t)((b * 4 + hh) * 512 + s0)) * 10 + f * 4);
        const int fo = f * 4;
        float e[4] = {u.x, u.y, u.z, u.w};
#pragma unroll
        for (int t = 0; t < 4; t++) {
            const int fe = fo + t;
            const int r = fe / 10, c = fe - r * 10;
            sCtx[r][hh * 10 + c] = e[t];
        }
    }
    const float4* xblk = (const float4*)(x + (size_t)blockIdx.x * 64 * 40);
    for (int idx = tid; idx < 640; idx += 256) {
        float4 w = xblk[idx];
        int fl = idx * 4;
        int r = fl / 40, c = fl - r * 40;
        sH[r][c] = w.x; sH[r][c + 1] = w.y; sH[r][c + 2] = w.z; sH[r][c + 3] = w.w;
    }
    __syncthreads();

    const int lane = tid & 63;
    const int wv = tid >> 6;
    const int j0 = wv * 10;

    float acc[10];
#pragma unroll
    for (int j = 0; j < 10; j++) acc[j] = sBo[j0 + j] + sH[lane][j0 + j];
#pragma unroll 8
    for (int i = 0; i < 40; i++) {
        const float ci = sCtx[lane][i];
        const float4* wrow = (const float4*)&sWo[i][wv * 12];
        float4 w0 = wrow[0], w1 = wrow[1], w2 = wrow[2];
        acc[0] += ci * w0.x; acc[1] += ci * w0.y; acc[2] += ci * w0.z; acc[3] += ci * w0.w;
        acc[4] += ci * w1.x; acc[5] += ci * w1.y; acc[6] += ci * w1.z; acc[7] += ci * w1.w;
        acc[8] += ci * w2.x; acc[9] += ci * w2.y;
    }
    {
        float s1 = 0.f, s2 = 0.f;
#pragma unroll
        for (int j = 0; j < 10; j++) { s1 += acc[j]; s2 += acc[j] * acc[j]; }
        sSum[lane][wv] = s1; sSum2[lane][wv] = s2;
    }
    __syncthreads();
    const float mu = (sSum[lane][0] + sSum[lane][1] + sSum[lane][2] + sSum[lane][3]) * 0.025f;
    const float ex2 = (sSum2[lane][0] + sSum2[lane][1] + sSum2[lane][2] + sSum2[lane][3]) * 0.025f;
    const float rs = rsqrtf(ex2 - mu * mu + EPSF);
#pragma unroll
    for (int j = 0; j < 10; j++)
        sH[lane][j0 + j] = (acc[j] - mu) * rs * sG2[j0 + j] + sBt2[j0 + j];
    __syncthreads();

    const int f0 = wv * 5;
    float it[5];
#pragma unroll
    for (int j = 0; j < 5; j++) it[j] = sB1[f0 + j];
#pragma unroll 8
    for (int i = 0; i < 40; i++) {
        const float hi = sH[lane][i];
        const float4* wrow = (const float4*)&sW1[i][wv * 8];
        float4 w0 = wrow[0], w1 = wrow[1];
        it[0] += hi * w0.x; it[1] += hi * w0.y; it[2] += hi * w0.z; it[3] += hi * w0.w;
        it[4] += hi * w1.x;
    }
#pragma unroll
    for (int j = 0; j < 5; j++) {
        float t = it[j];
        sIt[lane][f0 + j] = 0.5f * t * (1.0f + erff(t * 0.70710678118654752f));
    }
    __syncthreads();

    float o[10];
#pragma unroll
    for (int j = 0; j < 10; j++) o[j] = acc[j] + sB2[j0 + j];
#pragma unroll 4
    for (int i = 0; i < 20; i++) {
        const float ii = sIt[lane][i];
        const float4* wrow = (const float4*)&sW2[i][wv * 12];
        float4 w0 = wrow[0], w1 = wrow[1], w2 = wrow[2];
        o[0] += ii * w0.x; o[1] += ii * w0.y; o[2] += ii * w0.z; o[3] += ii * w0.w;
        o[4] += ii * w1.x; o[5] += ii * w1.y; o[6] += ii * w1.z; o[7] += ii * w1.w;
        o[8] += ii * w2.x; o[9] += ii * w2.y;
    }
#pragma unroll
    for (int j = 0; j < 10; j++) sCtx[lane][j0 + j] = o[j];
    __syncthreads();

    float4* oblk = (float4*)(out + (size_t)blockIdx.x * 64 * 40);
    for (int idx = tid; idx < 640; idx += 256) {
        int fl = idx * 4;
        int r = fl / 40, c = fl - r * 40;
        float4 u;
        u.x = sCtx[r][c]; u.y = sCtx[r][c + 1]; u.z = sCtx[r][c + 2]; u.w = sCtx[r][c + 3];
        oblk[idx] = u;
    }
}

extern "C" void kernel_launch(void* const* d_in, const int* in_sizes, int n_in,
                              void* d_out, int out_size, void* d_ws, size_t ws_size,
                              hipStream_t stream)
{
    const float* x   = (const float*)d_in[0];
    const float* g1  = (const float*)d_in[1];
    const float* be1 = (const float*)d_in[2];
    const float* Wq  = (const float*)d_in[3];
    const float* bq  = (const float*)d_in[4];
    const float* Wk  = (const float*)d_in[5];
    const float* bk  = (const float*)d_in[6];
    const float* Wv  = (const float*)d_in[7];
    const float* bv  = (const float*)d_in[8];
    const float* Wo  = (const float*)d_in[9];
    const float* bo  = (const float*)d_in[10];
    const float* g2  = (const float*)d_in[11];
    const float* bt2 = (const float*)d_in[12];
    const float* W1  = (const float*)d_in[13];
    const float* b1  = (const float*)d_in[14];
    const float* W2  = (const float*)d_in[15];
    const float* b2  = (const float*)d_in[16];

    float* ws = (float*)d_ws;
    const size_t QKV = (size_t)BB * 4 * SS * DPP;  // 1,572,864 floats
    float* q   = ws;
    float* k   = ws + QKV;
    float* v   = ws + 2 * QKV;
    float* ctx = ws + 3 * QKV;  // [B,H,S,10] = 1,310,720 floats

    k_ln_qkv<<<512, 256, 0, stream>>>(x, g1, be1, Wq, bq, Wk, bk, Wv, bv, q, k, v);
    k_attn<<<512, 512, 0, stream>>>(q, k, v, ctx);
    k_out_ffn<<<512, 256, 0, stream>>>(ctx, x, Wo, bo, g2, bt2, W1, b1, W2, b2,
                                       (float*)d_out);
}

// Round 10
// 212.628 us; speedup vs baseline: 1.2041x; 1.2041x over previous
//
#include <hip/hip_runtime.h>
#include <stdint.h>

#define BB 64
#define SS 512
#define EPSF 1e-5f

typedef float v2f __attribute__((ext_vector_type(2)));

// ---------------- K1: LN1 + QKV projection ----------------
// grid 512 x 256. Block = 64 rows; wave = j-part (32 cols), lane = row.
// Outputs q,k,v packed [B, H, S, 10] (no pad).
__global__ __launch_bounds__(256) void k_ln_qkv(
    const float* __restrict__ x, const float* __restrict__ g, const float* __restrict__ be,
    const float* __restrict__ Wq, const float* __restrict__ bq,
    const float* __restrict__ Wk, const float* __restrict__ bk,
    const float* __restrict__ Wv, const float* __restrict__ bv,
    float* __restrict__ qo, float* __restrict__ ko, float* __restrict__ vo)
{
    __shared__ float sWT[40][128];   // [i][j], j=0..119 valid (q|k|v), 120..127 zero
    __shared__ float sBias[128];
    __shared__ float sG[40], sBt[40];
    __shared__ float sX[64][41];
    __shared__ float sOut[64][129];

    const int tid = threadIdx.x;
    for (int idx = tid; idx < 5120; idx += 256) {
        int i = idx >> 7, j = idx & 127;
        float val = 0.f;
        if (j < 40)       val = Wq[i * 40 + j];
        else if (j < 80)  val = Wk[i * 40 + (j - 40)];
        else if (j < 120) val = Wv[i * 40 + (j - 80)];
        sWT[i][j] = val;
    }
    if (tid < 128) {
        int j = tid;
        float val = 0.f;
        if (j < 40)       val = bq[j];
        else if (j < 80)  val = bk[j - 40];
        else if (j < 120) val = bv[j - 80];
        sBias[j] = val;
    }
    if (tid < 40) { sG[tid] = g[tid]; sBt[tid] = be[tid]; }

    const float4* xblk = (const float4*)(x + (size_t)blockIdx.x * 64 * 40);
    for (int idx = tid; idx < 640; idx += 256) {
        float4 u = xblk[idx];
        int fl = idx * 4;
        int r = fl / 40, c = fl - r * 40;
        sX[r][c] = u.x; sX[r][c + 1] = u.y; sX[r][c + 2] = u.z; sX[r][c + 3] = u.w;
    }
    __syncthreads();

    const int lane = tid & 63;
    const int part = tid >> 6;
    const int j0 = part * 32;

    float s1 = 0.f, s2 = 0.f;
#pragma unroll 8
    for (int i = 0; i < 40; i++) { float v = sX[lane][i]; s1 += v; s2 += v * v; }
    const float mu = s1 * 0.025f;
    const float rs = rsqrtf(s2 * 0.025f - mu * mu + EPSF);

    float acc[32];
#pragma unroll
    for (int jj = 0; jj < 32; jj++) acc[jj] = sBias[j0 + jj];
#pragma unroll 4
    for (int i = 0; i < 40; i++) {
        const float hi = (sX[lane][i] - mu) * rs * sG[i] + sBt[i];
        const float4* wrow = (const float4*)&sWT[i][j0];
#pragma unroll
        for (int c = 0; c < 8; c++) {
            float4 wv = wrow[c];
            acc[c * 4 + 0] += hi * wv.x;
            acc[c * 4 + 1] += hi * wv.y;
            acc[c * 4 + 2] += hi * wv.z;
            acc[c * 4 + 3] += hi * wv.w;
        }
    }
#pragma unroll
    for (int jj = 0; jj < 32; jj++) sOut[lane][j0 + jj] = acc[jj];
    __syncthreads();

    // coalesced flush: 12 regions (q/k/v x 4 heads), each 64 rows x 10 floats
    // = 640 contiguous floats in global = 160 float4. 1920 float4 total.
    const int row0 = blockIdx.x * 64;
    const int b4 = (row0 >> 9) * 4, s0 = row0 & 511;
    for (int fi = tid; fi < 1920; fi += 256) {
        int region = fi / 160;
        int f = fi - region * 160;
        int w = region >> 2, hh = region & 3;
        float val4[4];
#pragma unroll
        for (int t = 0; t < 4; t++) {
            int fe = f * 4 + t;
            int r = fe / 10, c = fe - r * 10;
            val4[t] = sOut[r][w * 40 + hh * 10 + c];
        }
        float* op = ((w == 0) ? qo : (w == 1) ? ko : vo)
                    + ((size_t)((b4 + hh) * 512 + s0)) * 10 + f * 4;
        float4 u; u.x = val4[0]; u.y = val4[1]; u.z = val4[2]; u.w = val4[3];
        *(float4*)op = u;
    }
}

// ---------------- K2: attention v10 ----------------
// grid 512 = bh x q-half (256 q). block 512 = 8 waves = k-eighths (64 keys,
// 32 pairs). QPT=4. Packed-10 K/V staged in 40KB LDS (10 b128 per pair).
// launch_bounds(512,2): 128-VGPR cap, live state ~115 -> no spill.
// Merge: column-major LDS atomics aliased onto dead staging buffer.
__global__ __launch_bounds__(512, 2) void k_attn(
    const float* __restrict__ qg, const float* __restrict__ kg,
    const float* __restrict__ vg, float* __restrict__ ctx)
{
    __shared__ float smem[10240];        // 40KB: K[5120]+V[5120]; alias sAcc[11][256]

    const int tid = threadIdx.x;
    const int bh = blockIdx.x >> 1;
    const int qh = blockIdx.x & 1;

    {   // stage K/V: 1280 float4 each, coalesced
        const float4* kp = (const float4*)(kg + (size_t)bh * 5120);
        const float4* vp = (const float4*)(vg + (size_t)bh * 5120);
        float4* sK4 = (float4*)smem;
        float4* sV4 = (float4*)(smem + 5120);
        for (int idx = tid; idx < 1280; idx += 512) { sK4[idx] = kp[idx]; sV4[idx] = vp[idx]; }
    }

    const int lane = tid & 63;
    const int wave = tid >> 6;           // k-eighth: 64 keys = 32 pairs

    const float cscale = 1.4426950408889634f / 3.1622776601683795f;  // log2e/sqrt(10)
    v2f q[4][5];
#pragma unroll
    for (int jj = 0; jj < 4; jj++) {
        const float2* qp = (const float2*)(qg + ((size_t)bh * 512 + qh * 256 + jj * 64 + lane) * 10);
#pragma unroll
        for (int c = 0; c < 5; c++) {
            float2 u = qp[c];
            v2f t; t.x = u.x * cscale; t.y = u.y * cscale;
            q[jj][c] = t;
        }
    }

    float l[4] = {0.f, 0.f, 0.f, 0.f};
    v2f a[4][5];
#pragma unroll
    for (int jj = 0; jj < 4; jj++)
#pragma unroll
        for (int d = 0; d < 5; d++) a[jj][d] = (v2f)(0.f);

    __syncthreads();

    const float4* sKp = (const float4*)smem + (size_t)wave * 160;          // 64 keys x 10 fl
    const float4* sVp = (const float4*)(smem + 5120) + (size_t)wave * 160;

    for (int kt = 0; kt < 32; kt++) {
        // K pair: 20 floats = 5 float4. ka = k0.xy,k0.zw,k1.xy,k1.zw,k2.xy;
        // kb = k2.zw,k3.xy,k3.zw,k4.xy,k4.zw
        const float4 k0 = sKp[kt * 5 + 0], k1 = sKp[kt * 5 + 1], k2 = sKp[kt * 5 + 2];
        const float4 k3 = sKp[kt * 5 + 3], k4 = sKp[kt * 5 + 4];
        float pa[4], pb[4];
#pragma unroll
        for (int jj = 0; jj < 4; jj++) {
            v2f da = q[jj][0] * v2f{k0.x, k0.y};
            da += q[jj][1] * v2f{k0.z, k0.w};
            da += q[jj][2] * v2f{k1.x, k1.y};
            da += q[jj][3] * v2f{k1.z, k1.w};
            da += q[jj][4] * v2f{k2.x, k2.y};
            v2f db = q[jj][0] * v2f{k2.z, k2.w};
            db += q[jj][1] * v2f{k3.x, k3.y};
            db += q[jj][2] * v2f{k3.z, k3.w};
            db += q[jj][3] * v2f{k4.x, k4.y};
            db += q[jj][4] * v2f{k4.z, k4.w};
            pa[jj] = __builtin_amdgcn_exp2f(da.x + da.y);
            pb[jj] = __builtin_amdgcn_exp2f(db.x + db.y);
            l[jj] += pa[jj] + pb[jj];
        }
        // V pair (K regs dead -> reuse)
        const float4 v0 = sVp[kt * 5 + 0], v1 = sVp[kt * 5 + 1], v2 = sVp[kt * 5 + 2];
        const float4 v3 = sVp[kt * 5 + 3], v4 = sVp[kt * 5 + 4];
#pragma unroll
        for (int jj = 0; jj < 4; jj++) {
            const v2f pa2 = {pa[jj], pa[jj]};
            const v2f pb2 = {pb[jj], pb[jj]};
            a[jj][0] += pa2 * v2f{v0.x, v0.y};
            a[jj][1] += pa2 * v2f{v0.z, v0.w};
            a[jj][2] += pa2 * v2f{v1.x, v1.y};
            a[jj][3] += pa2 * v2f{v1.z, v1.w};
            a[jj][4] += pa2 * v2f{v2.x, v2.y};
            a[jj][0] += pb2 * v2f{v2.z, v2.w};
            a[jj][1] += pb2 * v2f{v3.x, v3.y};
            a[jj][2] += pb2 * v2f{v3.z, v3.w};
            a[jj][3] += pb2 * v2f{v4.x, v4.y};
            a[jj][4] += pb2 * v2f{v4.z, v4.w};
        }
    }
    __syncthreads();   // all sK/sV reads done -> safe to alias

    // zero merge buffer sAcc[11][256] = smem[0..2815]
    for (int idx = tid; idx < 2816; idx += 512) smem[idx] = 0.f;
    __syncthreads();

    // column-major atomic merge: lanes hit consecutive addresses
#pragma unroll
    for (int jj = 0; jj < 4; jj++) {
        const int qq = jj * 64 + lane;
        atomicAdd(&smem[0 * 256 + qq], a[jj][0].x);
        atomicAdd(&smem[1 * 256 + qq], a[jj][0].y);
        atomicAdd(&smem[2 * 256 + qq], a[jj][1].x);
        atomicAdd(&smem[3 * 256 + qq], a[jj][1].y);
        atomicAdd(&smem[4 * 256 + qq], a[jj][2].x);
        atomicAdd(&smem[5 * 256 + qq], a[jj][2].y);
        atomicAdd(&smem[6 * 256 + qq], a[jj][3].x);
        atomicAdd(&smem[7 * 256 + qq], a[jj][3].y);
        atomicAdd(&smem[8 * 256 + qq], a[jj][4].x);
        atomicAdd(&smem[9 * 256 + qq], a[jj][4].y);
        atomicAdd(&smem[10 * 256 + qq], l[jj]);
    }
    __syncthreads();

    // normalize + write: threads 0..255, one query each
    if (tid < 256) {
        const float inv = 1.f / smem[10 * 256 + tid];
        float* op = ctx + ((size_t)bh * 512 + qh * 256 + tid) * 10;
#pragma unroll
        for (int d = 0; d < 5; d++) {
            float2 w;
            w.x = smem[(d * 2 + 0) * 256 + tid] * inv;
            w.y = smem[(d * 2 + 1) * 256 + tid] * inv;
            *(float2*)(op + d * 2) = w;
        }
    }
}

// ---------------- K3: Wo + residual + LN2 + FFN + residual ----------------
// grid 512 x 256. Block = 64 rows; wave = col-slice, lane = row.
__global__ __launch_bounds__(256) void k_out_ffn(
    const float* __restrict__ ctx, const float* __restrict__ x,
    const float* __restrict__ Wo, const float* __restrict__ bo,
    const float* __restrict__ g2, const float* __restrict__ bt2,
    const float* __restrict__ W1, const float* __restrict__ b1,
    const float* __restrict__ W2, const float* __restrict__ b2,
    float* __restrict__ out)
{
    __shared__ float sWo[40][48];
    __shared__ float sW1[40][32];
    __shared__ float sW2[20][48];
    __shared__ float sBo[40], sG2[40], sBt2[40], sB1[20], sB2[40];
    __shared__ float sCtx[64][41];
    __shared__ float sH[64][41];
    __shared__ float sIt[64][21];
    __shared__ float sSum[64][4], sSum2[64][4];

    const int tid = threadIdx.x;
    for (int idx = tid; idx < 1600; idx += 256) {
        int i = idx / 40, j = idx % 40;
        sWo[i][(j / 10) * 12 + (j % 10)] = Wo[idx];
    }
    for (int idx = tid; idx < 800; idx += 256) {
        {
            int i = idx / 20, j = idx % 20;
            sW1[i][(j / 5) * 8 + (j % 5)] = W1[idx];
        }
        {
            int i = idx / 40, j = idx % 40;
            sW2[i][(j / 10) * 12 + (j % 10)] = W2[idx];
        }
    }
    if (tid < 40) { sBo[tid] = bo[tid]; sG2[tid] = g2[tid]; sBt2[tid] = bt2[tid]; sB2[tid] = b2[tid]; }
    if (tid < 20) sB1[tid] = b1[tid];

    const int row0 = blockIdx.x * 64;
    const int b = row0 >> 9, s0 = row0 & 511;

    // gather-stage ctx [B,H,S,10]: 4 heads x 160 contiguous float4 each
    for (int idx = tid; idx < 640; idx += 256) {
        const int hh = idx / 160, f = idx - hh * 160;
        float4 u = *(const float4*)(ctx + ((size_t)((b * 4 + hh) * 512 + s0)) * 10 + f * 4);
        const int fo = f * 4;
        float e[4] = {u.x, u.y, u.z, u.w};
#pragma unroll
        for (int t = 0; t < 4; t++) {
            const int fe = fo + t;
            const int r = fe / 10, c = fe - r * 10;
            sCtx[r][hh * 10 + c] = e[t];
        }
    }
    const float4* xblk = (const float4*)(x + (size_t)blockIdx.x * 64 * 40);
    for (int idx = tid; idx < 640; idx += 256) {
        float4 w = xblk[idx];
        int fl = idx * 4;
        int r = fl / 40, c = fl - r * 40;
        sH[r][c] = w.x; sH[r][c + 1] = w.y; sH[r][c + 2] = w.z; sH[r][c + 3] = w.w;
    }
    __syncthreads();

    const int lane = tid & 63;
    const int wv = tid >> 6;
    const int j0 = wv * 10;

    float acc[10];
#pragma unroll
    for (int j = 0; j < 10; j++) acc[j] = sBo[j0 + j] + sH[lane][j0 + j];
#pragma unroll 8
    for (int i = 0; i < 40; i++) {
        const float ci = sCtx[lane][i];
        const float4* wrow = (const float4*)&sWo[i][wv * 12];
        float4 w0 = wrow[0], w1 = wrow[1], w2 = wrow[2];
        acc[0] += ci * w0.x; acc[1] += ci * w0.y; acc[2] += ci * w0.z; acc[3] += ci * w0.w;
        acc[4] += ci * w1.x; acc[5] += ci * w1.y; acc[6] += ci * w1.z; acc[7] += ci * w1.w;
        acc[8] += ci * w2.x; acc[9] += ci * w2.y;
    }
    {
        float s1 = 0.f, s2 = 0.f;
#pragma unroll
        for (int j = 0; j < 10; j++) { s1 += acc[j]; s2 += acc[j] * acc[j]; }
        sSum[lane][wv] = s1; sSum2[lane][wv] = s2;
    }
    __syncthreads();
    const float mu = (sSum[lane][0] + sSum[lane][1] + sSum[lane][2] + sSum[lane][3]) * 0.025f;
    const float ex2 = (sSum2[lane][0] + sSum2[lane][1] + sSum2[lane][2] + sSum2[lane][3]) * 0.025f;
    const float rs = rsqrtf(ex2 - mu * mu + EPSF);
#pragma unroll
    for (int j = 0; j < 10; j++)
        sH[lane][j0 + j] = (acc[j] - mu) * rs * sG2[j0 + j] + sBt2[j0 + j];
    __syncthreads();

    const int f0 = wv * 5;
    float it[5];
#pragma unroll
    for (int j = 0; j < 5; j++) it[j] = sB1[f0 + j];
#pragma unroll 8
    for (int i = 0; i < 40; i++) {
        const float hi = sH[lane][i];
        const float4* wrow = (const float4*)&sW1[i][wv * 8];
        float4 w0 = wrow[0], w1 = wrow[1];
        it[0] += hi * w0.x; it[1] += hi * w0.y; it[2] += hi * w0.z; it[3] += hi * w0.w;
        it[4] += hi * w1.x;
    }
#pragma unroll
    for (int j = 0; j < 5; j++) {
        float t = it[j];
        sIt[lane][f0 + j] = 0.5f * t * (1.0f + erff(t * 0.70710678118654752f));
    }
    __syncthreads();

    float o[10];
#pragma unroll
    for (int j = 0; j < 10; j++) o[j] = acc[j] + sB2[j0 + j];
#pragma unroll 4
    for (int i = 0; i < 20; i++) {
        const float ii = sIt[lane][i];
        const float4* wrow = (const float4*)&sW2[i][wv * 12];
        float4 w0 = wrow[0], w1 = wrow[1], w2 = wrow[2];
        o[0] += ii * w0.x; o[1] += ii * w0.y; o[2] += ii * w0.z; o[3] += ii * w0.w;
        o[4] += ii * w1.x; o[5] += ii * w1.y; o[6] += ii * w1.z; o[7] += ii * w1.w;
        o[8] += ii * w2.x; o[9] += ii * w2.y;
    }
#pragma unroll
    for (int j = 0; j < 10; j++) sCtx[lane][j0 + j] = o[j];
    __syncthreads();

    float4* oblk = (float4*)(out + (size_t)blockIdx.x * 64 * 40);
    for (int idx = tid; idx < 640; idx += 256) {
        int fl = idx * 4;
        int r = fl / 40, c = fl - r * 40;
        float4 u;
        u.x = sCtx[r][c]; u.y = sCtx[r][c + 1]; u.z = sCtx[r][c + 2]; u.w = sCtx[r][c + 3];
        oblk[idx] = u;
    }
}

extern "C" void kernel_launch(void* const* d_in, const int* in_sizes, int n_in,
                              void* d_out, int out_size, void* d_ws, size_t ws_size,
                              hipStream_t stream)
{
    const float* x   = (const float*)d_in[0];
    const float* g1  = (const float*)d_in[1];
    const float* be1 = (const float*)d_in[2];
    const float* Wq  = (const float*)d_in[3];
    const float* bq  = (const float*)d_in[4];
    const float* Wk  = (const float*)d_in[5];
    const float* bk  = (const float*)d_in[6];
    const float* Wv  = (const float*)d_in[7];
    const float* bv  = (const float*)d_in[8];
    const float* Wo  = (const float*)d_in[9];
    const float* bo  = (const float*)d_in[10];
    const float* g2  = (const float*)d_in[11];
    const float* bt2 = (const float*)d_in[12];
    const float* W1  = (const float*)d_in[13];
    const float* b1  = (const float*)d_in[14];
    const float* W2  = (const float*)d_in[15];
    const float* b2  = (const float*)d_in[16];

    float* ws = (float*)d_ws;
    const size_t QKV = (size_t)BB * 4 * SS * 10;  // 1,310,720 floats (packed-10)
    float* q   = ws;
    float* k   = ws + QKV;
    float* v   = ws + 2 * QKV;
    float* ctx = ws + 3 * QKV;  // [B,H,S,10]

    k_ln_qkv<<<512, 256, 0, stream>>>(x, g1, be1, Wq, bq, Wk, bk, Wv, bv, q, k, v);
    k_attn<<<512, 512, 0, stream>>>(q, k, v, ctx);
    k_out_ffn<<<512, 256, 0, stream>>>(ctx, x, Wo, bo, g2, bt2, W1, b1, W2, b2,
                                       (float*)d_out);
}

// Round 11
// 186.568 us; speedup vs baseline: 1.3723x; 1.1397x over previous
//
#include <hip/hip_runtime.h>
#include <stdint.h>

#define BB 64
#define SS 512
#define EPSF 1e-5f

typedef float v2f __attribute__((ext_vector_type(2)));

// ---------------- K1: LN1 + QKV projection ----------------
// grid 512 x 256. Block = 64 rows; wave = j-part (32 cols), lane = row.
// Outputs q,k,v packed [B, H, S, 10] (no pad).
__global__ __launch_bounds__(256) void k_ln_qkv(
    const float* __restrict__ x, const float* __restrict__ g, const float* __restrict__ be,
    const float* __restrict__ Wq, const float* __restrict__ bq,
    const float* __restrict__ Wk, const float* __restrict__ bk,
    const float* __restrict__ Wv, const float* __restrict__ bv,
    float* __restrict__ qo, float* __restrict__ ko, float* __restrict__ vo)
{
    __shared__ float sWT[40][128];   // [i][j], j=0..119 valid (q|k|v), 120..127 zero
    __shared__ float sBias[128];
    __shared__ float sG[40], sBt[40];
    __shared__ float sX[64][41];
    __shared__ float sOut[64][129];

    const int tid = threadIdx.x;
    for (int idx = tid; idx < 5120; idx += 256) {
        int i = idx >> 7, j = idx & 127;
        float val = 0.f;
        if (j < 40)       val = Wq[i * 40 + j];
        else if (j < 80)  val = Wk[i * 40 + (j - 40)];
        else if (j < 120) val = Wv[i * 40 + (j - 80)];
        sWT[i][j] = val;
    }
    if (tid < 128) {
        int j = tid;
        float val = 0.f;
        if (j < 40)       val = bq[j];
        else if (j < 80)  val = bk[j - 40];
        else if (j < 120) val = bv[j - 80];
        sBias[j] = val;
    }
    if (tid < 40) { sG[tid] = g[tid]; sBt[tid] = be[tid]; }

    const float4* xblk = (const float4*)(x + (size_t)blockIdx.x * 64 * 40);
    for (int idx = tid; idx < 640; idx += 256) {
        float4 u = xblk[idx];
        int fl = idx * 4;
        int r = fl / 40, c = fl - r * 40;
        sX[r][c] = u.x; sX[r][c + 1] = u.y; sX[r][c + 2] = u.z; sX[r][c + 3] = u.w;
    }
    __syncthreads();

    const int lane = tid & 63;
    const int part = tid >> 6;
    const int j0 = part * 32;

    float s1 = 0.f, s2 = 0.f;
#pragma unroll 8
    for (int i = 0; i < 40; i++) { float v = sX[lane][i]; s1 += v; s2 += v * v; }
    const float mu = s1 * 0.025f;
    const float rs = rsqrtf(s2 * 0.025f - mu * mu + EPSF);

    float acc[32];
#pragma unroll
    for (int jj = 0; jj < 32; jj++) acc[jj] = sBias[j0 + jj];
#pragma unroll 4
    for (int i = 0; i < 40; i++) {
        const float hi = (sX[lane][i] - mu) * rs * sG[i] + sBt[i];
        const float4* wrow = (const float4*)&sWT[i][j0];
#pragma unroll
        for (int c = 0; c < 8; c++) {
            float4 wv = wrow[c];
            acc[c * 4 + 0] += hi * wv.x;
            acc[c * 4 + 1] += hi * wv.y;
            acc[c * 4 + 2] += hi * wv.z;
            acc[c * 4 + 3] += hi * wv.w;
        }
    }
#pragma unroll
    for (int jj = 0; jj < 32; jj++) sOut[lane][j0 + jj] = acc[jj];
    __syncthreads();

    // coalesced flush: 12 regions (q/k/v x 4 heads), each 64 rows x 10 floats
    const int row0 = blockIdx.x * 64;
    const int b4 = (row0 >> 9) * 4, s0 = row0 & 511;
    for (int fi = tid; fi < 1920; fi += 256) {
        int region = fi / 160;
        int f = fi - region * 160;
        int w = region >> 2, hh = region & 3;
        float val4[4];
#pragma unroll
        for (int t = 0; t < 4; t++) {
            int fe = f * 4 + t;
            int r = fe / 10, c = fe - r * 10;
            val4[t] = sOut[r][w * 40 + hh * 10 + c];
        }
        float* op = ((w == 0) ? qo : (w == 1) ? ko : vo)
                    + ((size_t)((b4 + hh) * 512 + s0)) * 10 + f * 4;
        float4 u; u.x = val4[0]; u.y = val4[1]; u.z = val4[2]; u.w = val4[3];
        *(float4*)op = u;
    }
}

// ---------------- K2: attention v11 ----------------
// grid 1024 = bh x q-quarter (128 q). block 256 = 4 waves = k-quarters
// (128 keys = 64 pairs). QPT=2. Packed-10 K/V staged in 40KB LDS ->
// 4 blocks/CU (160KB exactly), 16 waves/CU. 256-thr block avoids the
// 512-thr 64-VGPR cap (R9/R10 evidence). Merge: column-major LDS atomics
// aliased onto the dead staging buffer.
__global__ __launch_bounds__(256) void k_attn(
    const float* __restrict__ qg, const float* __restrict__ kg,
    const float* __restrict__ vg, float* __restrict__ ctx)
{
    __shared__ float smem[10240];        // 40KB: K[5120]+V[5120]; alias sAcc[11][128]

    const int tid = threadIdx.x;
    const int bh = blockIdx.x >> 2;
    const int qq = blockIdx.x & 3;       // q-quarter: 128 queries

    {   // stage K/V: 1280 float4 each, coalesced
        const float4* kp = (const float4*)(kg + (size_t)bh * 5120);
        const float4* vp = (const float4*)(vg + (size_t)bh * 5120);
        float4* sK4 = (float4*)smem;
        float4* sV4 = (float4*)(smem + 5120);
        for (int idx = tid; idx < 1280; idx += 256) { sK4[idx] = kp[idx]; sV4[idx] = vp[idx]; }
    }

    const int lane = tid & 63;
    const int wave = tid >> 6;           // k-quarter: 128 keys = 64 pairs

    const float cscale = 1.4426950408889634f / 3.1622776601683795f;  // log2e/sqrt(10)
    v2f q[2][5];
#pragma unroll
    for (int jj = 0; jj < 2; jj++) {
        const float2* qp = (const float2*)(qg + ((size_t)bh * 512 + qq * 128 + jj * 64 + lane) * 10);
#pragma unroll
        for (int c = 0; c < 5; c++) {
            float2 u = qp[c];
            v2f t; t.x = u.x * cscale; t.y = u.y * cscale;
            q[jj][c] = t;
        }
    }

    float l[2] = {0.f, 0.f};
    v2f a[2][5];
#pragma unroll
    for (int jj = 0; jj < 2; jj++)
#pragma unroll
        for (int d = 0; d < 5; d++) a[jj][d] = (v2f)(0.f);

    __syncthreads();

    // slice of 64 key-pairs: pair kt occupies float4 [kt*5 .. kt*5+4]
    const float4* sKp = (const float4*)smem + (size_t)wave * 320;
    const float4* sVp = (const float4*)(smem + 5120) + (size_t)wave * 320;

#pragma unroll 2
    for (int kt = 0; kt < 64; kt++) {
        const float4 k0 = sKp[kt * 5 + 0], k1 = sKp[kt * 5 + 1], k2 = sKp[kt * 5 + 2];
        const float4 k3 = sKp[kt * 5 + 3], k4 = sKp[kt * 5 + 4];
        float pa[2], pb[2];
#pragma unroll
        for (int jj = 0; jj < 2; jj++) {
            v2f da = q[jj][0] * v2f{k0.x, k0.y};
            da += q[jj][1] * v2f{k0.z, k0.w};
            da += q[jj][2] * v2f{k1.x, k1.y};
            da += q[jj][3] * v2f{k1.z, k1.w};
            da += q[jj][4] * v2f{k2.x, k2.y};
            v2f db = q[jj][0] * v2f{k2.z, k2.w};
            db += q[jj][1] * v2f{k3.x, k3.y};
            db += q[jj][2] * v2f{k3.z, k3.w};
            db += q[jj][3] * v2f{k4.x, k4.y};
            db += q[jj][4] * v2f{k4.z, k4.w};
            pa[jj] = __builtin_amdgcn_exp2f(da.x + da.y);
            pb[jj] = __builtin_amdgcn_exp2f(db.x + db.y);
            l[jj] += pa[jj] + pb[jj];
        }
        const float4 v0 = sVp[kt * 5 + 0], v1 = sVp[kt * 5 + 1], v2 = sVp[kt * 5 + 2];
        const float4 v3 = sVp[kt * 5 + 3], v4 = sVp[kt * 5 + 4];
#pragma unroll
        for (int jj = 0; jj < 2; jj++) {
            const v2f pa2 = {pa[jj], pa[jj]};
            const v2f pb2 = {pb[jj], pb[jj]};
            a[jj][0] += pa2 * v2f{v0.x, v0.y};
            a[jj][1] += pa2 * v2f{v0.z, v0.w};
            a[jj][2] += pa2 * v2f{v1.x, v1.y};
            a[jj][3] += pa2 * v2f{v1.z, v1.w};
            a[jj][4] += pa2 * v2f{v2.x, v2.y};
            a[jj][0] += pb2 * v2f{v2.z, v2.w};
            a[jj][1] += pb2 * v2f{v3.x, v3.y};
            a[jj][2] += pb2 * v2f{v3.z, v3.w};
            a[jj][3] += pb2 * v2f{v4.x, v4.y};
            a[jj][4] += pb2 * v2f{v4.z, v4.w};
        }
    }
    __syncthreads();   // all sK/sV reads done -> safe to alias

    // zero merge buffer sAcc[11][128] = smem[0..1407]
    for (int idx = tid; idx < 1408; idx += 256) smem[idx] = 0.f;
    __syncthreads();

    // column-major atomic merge: lanes hit consecutive addresses
#pragma unroll
    for (int jj = 0; jj < 2; jj++) {
        const int qx = jj * 64 + lane;
        atomicAdd(&smem[0 * 128 + qx], a[jj][0].x);
        atomicAdd(&smem[1 * 128 + qx], a[jj][0].y);
        atomicAdd(&smem[2 * 128 + qx], a[jj][1].x);
        atomicAdd(&smem[3 * 128 + qx], a[jj][1].y);
        atomicAdd(&smem[4 * 128 + qx], a[jj][2].x);
        atomicAdd(&smem[5 * 128 + qx], a[jj][2].y);
        atomicAdd(&smem[6 * 128 + qx], a[jj][3].x);
        atomicAdd(&smem[7 * 128 + qx], a[jj][3].y);
        atomicAdd(&smem[8 * 128 + qx], a[jj][4].x);
        atomicAdd(&smem[9 * 128 + qx], a[jj][4].y);
        atomicAdd(&smem[10 * 128 + qx], l[jj]);
    }
    __syncthreads();

    // normalize + write: threads 0..127, one query each
    if (tid < 128) {
        const float inv = 1.f / smem[10 * 128 + tid];
        float* op = ctx + ((size_t)bh * 512 + qq * 128 + tid) * 10;
#pragma unroll
        for (int d = 0; d < 5; d++) {
            float2 w;
            w.x = smem[(d * 2 + 0) * 128 + tid] * inv;
            w.y = smem[(d * 2 + 1) * 128 + tid] * inv;
            *(float2*)(op + d * 2) = w;
        }
    }
}

// ---------------- K3: Wo + residual + LN2 + FFN + residual ----------------
// grid 512 x 256. Block = 64 rows; wave = col-slice, lane = row.
__global__ __launch_bounds__(256) void k_out_ffn(
    const float* __restrict__ ctx, const float* __restrict__ x,
    const float* __restrict__ Wo, const float* __restrict__ bo,
    const float* __restrict__ g2, const float* __restrict__ bt2,
    const float* __restrict__ W1, const float* __restrict__ b1,
    const float* __restrict__ W2, const float* __restrict__ b2,
    float* __restrict__ out)
{
    __shared__ float sWo[40][48];
    __shared__ float sW1[40][32];
    __shared__ float sW2[20][48];
    __shared__ float sBo[40], sG2[40], sBt2[40], sB1[20], sB2[40];
    __shared__ float sCtx[64][41];
    __shared__ float sH[64][41];
    __shared__ float sIt[64][21];
    __shared__ float sSum[64][4], sSum2[64][4];

    const int tid = threadIdx.x;
    for (int idx = tid; idx < 1600; idx += 256) {
        int i = idx / 40, j = idx % 40;
        sWo[i][(j / 10) * 12 + (j % 10)] = Wo[idx];
    }
    for (int idx = tid; idx < 800; idx += 256) {
        {
            int i = idx / 20, j = idx % 20;
            sW1[i][(j / 5) * 8 + (j % 5)] = W1[idx];
        }
        {
            int i = idx / 40, j = idx % 40;
            sW2[i][(j / 10) * 12 + (j % 10)] = W2[idx];
        }
    }
    if (tid < 40) { sBo[tid] = bo[tid]; sG2[tid] = g2[tid]; sBt2[tid] = bt2[tid]; sB2[tid] = b2[tid]; }
    if (tid < 20) sB1[tid] = b1[tid];

    const int row0 = blockIdx.x * 64;
    const int b = row0 >> 9, s0 = row0 & 511;

    // gather-stage ctx [B,H,S,10]: 4 heads x 160 contiguous float4 each
    for (int idx = tid; idx < 640; idx += 256) {
        const int hh = idx / 160, f = idx - hh * 160;
        float4 u = *(const float4*)(ctx + ((size_t)((b * 4 + hh) * 512 + s0)) * 10 + f * 4);
        const int fo = f * 4;
        float e[4] = {u.x, u.y, u.z, u.w};
#pragma unroll
        for (int t = 0; t < 4; t++) {
            const int fe = fo + t;
            const int r = fe / 10, c = fe - r * 10;
            sCtx[r][hh * 10 + c] = e[t];
        }
    }
    const float4* xblk = (const float4*)(x + (size_t)blockIdx.x * 64 * 40);
    for (int idx = tid; idx < 640; idx += 256) {
        float4 w = xblk[idx];
        int fl = idx * 4;
        int r = fl / 40, c = fl - r * 40;
        sH[r][c] = w.x; sH[r][c + 1] = w.y; sH[r][c + 2] = w.z; sH[r][c + 3] = w.w;
    }
    __syncthreads();

    const int lane = tid & 63;
    const int wv = tid >> 6;
    const int j0 = wv * 10;

    float acc[10];
#pragma unroll
    for (int j = 0; j < 10; j++) acc[j] = sBo[j0 + j] + sH[lane][j0 + j];
#pragma unroll 8
    for (int i = 0; i < 40; i++) {
        const float ci = sCtx[lane][i];
        const float4* wrow = (const float4*)&sWo[i][wv * 12];
        float4 w0 = wrow[0], w1 = wrow[1], w2 = wrow[2];
        acc[0] += ci * w0.x; acc[1] += ci * w0.y; acc[2] += ci * w0.z; acc[3] += ci * w0.w;
        acc[4] += ci * w1.x; acc[5] += ci * w1.y; acc[6] += ci * w1.z; acc[7] += ci * w1.w;
        acc[8] += ci * w2.x; acc[9] += ci * w2.y;
    }
    {
        float s1 = 0.f, s2 = 0.f;
#pragma unroll
        for (int j = 0; j < 10; j++) { s1 += acc[j]; s2 += acc[j] * acc[j]; }
        sSum[lane][wv] = s1; sSum2[lane][wv] = s2;
    }
    __syncthreads();
    const float mu = (sSum[lane][0] + sSum[lane][1] + sSum[lane][2] + sSum[lane][3]) * 0.025f;
    const float ex2 = (sSum2[lane][0] + sSum2[lane][1] + sSum2[lane][2] + sSum2[lane][3]) * 0.025f;
    const float rs = rsqrtf(ex2 - mu * mu + EPSF);
#pragma unroll
    for (int j = 0; j < 10; j++)
        sH[lane][j0 + j] = (acc[j] - mu) * rs * sG2[j0 + j] + sBt2[j0 + j];
    __syncthreads();

    const int f0 = wv * 5;
    float it[5];
#pragma unroll
    for (int j = 0; j < 5; j++) it[j] = sB1[f0 + j];
#pragma unroll 8
    for (int i = 0; i < 40; i++) {
        const float hi = sH[lane][i];
        const float4* wrow = (const float4*)&sW1[i][wv * 8];
        float4 w0 = wrow[0], w1 = wrow[1];
        it[0] += hi * w0.x; it[1] += hi * w0.y; it[2] += hi * w0.z; it[3] += hi * w0.w;
        it[4] += hi * w1.x;
    }
#pragma unroll
    for (int j = 0; j < 5; j++) {
        float t = it[j];
        sIt[lane][f0 + j] = 0.5f * t * (1.0f + erff(t * 0.70710678118654752f));
    }
    __syncthreads();

    float o[10];
#pragma unroll
    for (int j = 0; j < 10; j++) o[j] = acc[j] + sB2[j0 + j];
#pragma unroll 4
    for (int i = 0; i < 20; i++) {
        const float ii = sIt[lane][i];
        const float4* wrow = (const float4*)&sW2[i][wv * 12];
        float4 w0 = wrow[0], w1 = wrow[1], w2 = wrow[2];
        o[0] += ii * w0.x; o[1] += ii * w0.y; o[2] += ii * w0.z; o[3] += ii * w0.w;
        o[4] += ii * w1.x; o[5] += ii * w1.y; o[6] += ii * w1.z; o[7] += ii * w1.w;
        o[8] += ii * w2.x; o[9] += ii * w2.y;
    }
#pragma unroll
    for (int j = 0; j < 10; j++) sCtx[lane][j0 + j] = o[j];
    __syncthreads();

    float4* oblk = (float4*)(out + (size_t)blockIdx.x * 64 * 40);
    for (int idx = tid; idx < 640; idx += 256) {
        int fl = idx * 4;
        int r = fl / 40, c = fl - r * 40;
        float4 u;
        u.x = sCtx[r][c]; u.y = sCtx[r][c + 1]; u.z = sCtx[r][c + 2]; u.w = sCtx[r][c + 3];
        oblk[idx] = u;
    }
}

extern "C" void kernel_launch(void* const* d_in, const int* in_sizes, int n_in,
                              void* d_out, int out_size, void* d_ws, size_t ws_size,
                              hipStream_t stream)
{
    const float* x   = (const float*)d_in[0];
    const float* g1  = (const float*)d_in[1];
    const float* be1 = (const float*)d_in[2];
    const float* Wq  = (const float*)d_in[3];
    const float* bq  = (const float*)d_in[4];
    const float* Wk  = (const float*)d_in[5];
    const float* bk  = (const float*)d_in[6];
    const float* Wv  = (const float*)d_in[7];
    const float* bv  = (const float*)d_in[8];
    const float* Wo  = (const float*)d_in[9];
    const float* bo  = (const float*)d_in[10];
    const float* g2  = (const float*)d_in[11];
    const float* bt2 = (const float*)d_in[12];
    const float* W1  = (const float*)d_in[13];
    const float* b1  = (const float*)d_in[14];
    const float* W2  = (const float*)d_in[15];
    const float* b2  = (const float*)d_in[16];

    float* ws = (float*)d_ws;
    const size_t QKV = (size_t)BB * 4 * SS * 10;  // 1,310,720 floats (packed-10)
    float* q   = ws;
    float* k   = ws + QKV;
    float* v   = ws + 2 * QKV;
    float* ctx = ws + 3 * QKV;  // [B,H,S,10]

    k_ln_qkv<<<512, 256, 0, stream>>>(x, g1, be1, Wq, bq, Wk, bk, Wv, bv, q, k, v);
    k_attn<<<1024, 256, 0, stream>>>(q, k, v, ctx);
    k_out_ffn<<<512, 256, 0, stream>>>(ctx, x, Wo, bo, g2, bt2, W1, b1, W2, b2,
                                       (float*)d_out);
}